// Round 3
// baseline (25.465 us; speedup 1.0000x reference)
//
#include <hip/hip_runtime.h>

// EP all-to-all dispatch+combine where the permutation round-trips to the
// identity: out[t,h] = (sum_k weights[t,k]) * input[t,h].
// T=8192, H=2048, K=8. Pure memory-bound row-scale.
//
// R3: same as R2 but using a native clang ext_vector float4 so the
// nontemporal builtins accept the pointer type.

#define T_TOK 8192
#define H_DIM 2048
#define NV_ROW (H_DIM / 4)        // 512 float4 per row
#define ROWS_PER_BLOCK 4

typedef float f4 __attribute__((ext_vector_type(4)));

__global__ __launch_bounds__(256) void ep_a2a_rowscale_kernel(
    const f4* __restrict__ in4,     // [T, H/4]
    const f4* __restrict__ w4,      // [T, 2]  (K=8 floats -> 2 f4)
    f4* __restrict__ o4)            // [T, H/4]
{
    const int t0  = blockIdx.x * ROWS_PER_BLOCK;
    const int tid = threadIdx.x;

    // Per-row weight sums (cached broadcast loads; reused by all 256 threads).
    float s[ROWS_PER_BLOCK];
#pragma unroll
    for (int r = 0; r < ROWS_PER_BLOCK; ++r) {
        const f4 wa = w4[(size_t)(t0 + r) * 2 + 0];
        const f4 wb = w4[(size_t)(t0 + r) * 2 + 1];
        s[r] = (wa.x + wa.y + wa.z + wa.w) + (wb.x + wb.y + wb.z + wb.w);
    }

    // 4 rows x 512 f4 / 256 threads = 8 independent load/store pairs.
    // Loads issued first (unrolled) so 8 VMEM reads are in flight together.
    f4 v[ROWS_PER_BLOCK][2];
#pragma unroll
    for (int r = 0; r < ROWS_PER_BLOCK; ++r) {
        const size_t base = (size_t)(t0 + r) * NV_ROW + tid;
        v[r][0] = __builtin_nontemporal_load(&in4[base]);
        v[r][1] = __builtin_nontemporal_load(&in4[base + 256]);
    }
#pragma unroll
    for (int r = 0; r < ROWS_PER_BLOCK; ++r) {
        const size_t base = (size_t)(t0 + r) * NV_ROW + tid;
        f4 a = v[r][0] * s[r];
        f4 b = v[r][1] * s[r];
        __builtin_nontemporal_store(a, &o4[base]);
        __builtin_nontemporal_store(b, &o4[base + 256]);
    }
}

extern "C" void kernel_launch(void* const* d_in, const int* in_sizes, int n_in,
                              void* d_out, int out_size, void* d_ws, size_t ws_size,
                              hipStream_t stream) {
    const f4* in4 = (const f4*)d_in[0];   // [T, H] fp32
    const f4* w4  = (const f4*)d_in[1];   // [T, K=8] fp32
    // d_in[2] (exp_indices) unused: dispatch permutation and inverse cancel.

    f4* o4 = (f4*)d_out;                  // [T, H] fp32

    ep_a2a_rowscale_kernel<<<dim3(T_TOK / ROWS_PER_BLOCK), dim3(256), 0, stream>>>(
        in4, w4, o4);
}

// Round 4
// 25.186 us; speedup vs baseline: 1.0111x; 1.0111x over previous
//
#include <hip/hip_runtime.h>

// EP all-to-all dispatch+combine where the permutation round-trips to the
// identity: out[t,h] = (sum_k weights[t,k]) * input[t,h].
// T=8192, H=2048, K=8. Pure memory-bound row-scale.
//
// R4: cached loads (input is 64 MiB -> L3-resident across timed replays;
// don't mark it evict-first), nontemporal STORES only (out is write-once
// streaming; skip L2 allocate pressure). 4096 blocks x 2 rows.

#define T_TOK 8192
#define H_DIM 2048
#define NV_ROW (H_DIM / 4)        // 512 float4 per row
#define ROWS_PER_BLOCK 2

typedef float f4 __attribute__((ext_vector_type(4)));

__global__ __launch_bounds__(256) void ep_a2a_rowscale_kernel(
    const f4* __restrict__ in4,     // [T, H/4]
    const f4* __restrict__ w4,      // [T, 2]  (K=8 floats -> 2 f4)
    f4* __restrict__ o4)            // [T, H/4]
{
    const int t0  = blockIdx.x * ROWS_PER_BLOCK;
    const int tid = threadIdx.x;

    // Per-row weight sums (cached broadcast loads; reused by all 256 threads).
    float s[ROWS_PER_BLOCK];
#pragma unroll
    for (int r = 0; r < ROWS_PER_BLOCK; ++r) {
        const f4 wa = w4[(size_t)(t0 + r) * 2 + 0];
        const f4 wb = w4[(size_t)(t0 + r) * 2 + 1];
        s[r] = (wa.x + wa.y + wa.z + wa.w) + (wb.x + wb.y + wb.z + wb.w);
    }

    // 2 rows x 512 f4 / 256 threads = 4 independent load/store pairs.
    // Cached loads issued first so all 4 VMEM reads are in flight together.
    f4 v[ROWS_PER_BLOCK][2];
#pragma unroll
    for (int r = 0; r < ROWS_PER_BLOCK; ++r) {
        const size_t base = (size_t)(t0 + r) * NV_ROW + tid;
        v[r][0] = in4[base];
        v[r][1] = in4[base + 256];
    }
#pragma unroll
    for (int r = 0; r < ROWS_PER_BLOCK; ++r) {
        const size_t base = (size_t)(t0 + r) * NV_ROW + tid;
        f4 a = v[r][0] * s[r];
        f4 b = v[r][1] * s[r];
        __builtin_nontemporal_store(a, &o4[base]);
        __builtin_nontemporal_store(b, &o4[base + 256]);
    }
}

extern "C" void kernel_launch(void* const* d_in, const int* in_sizes, int n_in,
                              void* d_out, int out_size, void* d_ws, size_t ws_size,
                              hipStream_t stream) {
    const f4* in4 = (const f4*)d_in[0];   // [T, H] fp32
    const f4* w4  = (const f4*)d_in[1];   // [T, K=8] fp32
    // d_in[2] (exp_indices) unused: dispatch permutation and inverse cancel.

    f4* o4 = (f4*)d_out;                  // [T, H] fp32

    ep_a2a_rowscale_kernel<<<dim3(T_TOK / ROWS_PER_BLOCK), dim3(256), 0, stream>>>(
        in4, w4, o4);
}